// Round 10
// baseline (443.419 us; speedup 1.0000x reference)
//
#include <hip/hip_runtime.h>
#include <math.h>

typedef unsigned short u16;
typedef __bf16 bf16x8 __attribute__((ext_vector_type(8)));
typedef float f32x4 __attribute__((ext_vector_type(4)));

// ---- constants ----
// B=4, N=1024, D=768, H=12, Dh=64, HID=2048, 3D=2304
#define NTOK 1024
#define DMODEL 768
#define NHEAD 12
#define LD3 2304
#define HIDDIM 2048

__device__ __forceinline__ float b2f(u16 u) {
  unsigned int t = ((unsigned int)u) << 16;
  float f;
  __builtin_memcpy(&f, &t, 4);
  return f;
}
__device__ __forceinline__ u16 f2b(float f) {
  unsigned int t;
  __builtin_memcpy(&t, &f, 4);
  t += 0x7fffu + ((t >> 16) & 1u);
  return (u16)(t >> 16);
}

// ---------------- host-assert signal (f32 output now) ------------------------
__global__ __launch_bounds__(256) void signal_kernel(float* __restrict__ out,
                                                     int n, float c) {
  int i = blockIdx.x * 256 + threadIdx.x;
  if (i < n) out[i] = c;
}

// ---------------- input dtype detection (verified f32: flag=1, R6) -----------
__global__ __launch_bounds__(256) void detect_kernel(const u16* __restrict__ x,
                                                     int* __restrict__ flag) {
  __shared__ int cnt;
  if (threadIdx.x == 0) cnt = 0;
  __syncthreads();
  int bad = 0;
  for (int i = threadIdx.x; i < 4096; i += 256) {
    u16 v = x[2 * i];
    int e = (v >> 7) & 0xFF;
    if (e >= 0xC0) bad++;
  }
  atomicAdd(&cnt, bad);
  __syncthreads();
  if (threadIdx.x == 0) *flag = (cnt >= 64) ? 1 : 0;
}

// ---------------- canonicalize all inputs to bf16 (linear, C-order) ----------
struct CanonJobs {
  const void* s[13];
  u16* d[13];
  int n[13];
};

__global__ __launch_bounds__(256) void canon_kernel(CanonJobs jobs,
                                                    const int* __restrict__ flag) {
  int j = blockIdx.y;
  int n = jobs.n[j];
  const void* s = jobs.s[j];
  u16* d = jobs.d[j];
  bool isf32 = (*flag != 0);
  for (int i = blockIdx.x * 256 + threadIdx.x; i < n; i += gridDim.x * 256) {
    d[i] = isf32 ? f2b(((const float*)s)[i]) : ((const u16*)s)[i];
  }
}

// ---------------- LayerNorm (bf16 input) ----------------
__global__ __launch_bounds__(256) void ln_bf16_kernel(
    const u16* __restrict__ x, const u16* __restrict__ g,
    const u16* __restrict__ b, u16* __restrict__ out) {
  int row = blockIdx.x;
  int tid = threadIdx.x;
  const u16* xr = x + (size_t)row * DMODEL;
  float v0 = b2f(xr[tid]), v1 = b2f(xr[tid + 256]), v2 = b2f(xr[tid + 512]);
  float s = v0 + v1 + v2;
  float q = v0 * v0 + v1 * v1 + v2 * v2;
#pragma unroll
  for (int off = 32; off; off >>= 1) {
    s += __shfl_xor(s, off, 64);
    q += __shfl_xor(q, off, 64);
  }
  __shared__ float rs[4], rq[4];
  int wv = tid >> 6;
  if ((tid & 63) == 0) { rs[wv] = s; rq[wv] = q; }
  __syncthreads();
  s = rs[0] + rs[1] + rs[2] + rs[3];
  q = rq[0] + rq[1] + rq[2] + rq[3];
  float mean = s * (1.0f / 768.0f);
  float var = q * (1.0f / 768.0f) - mean * mean;
  float inv = rsqrtf(var + 1e-5f);
  u16* outr = out + (size_t)row * DMODEL;
  outr[tid]       = f2b((v0 - mean) * inv * b2f(g[tid])       + b2f(b[tid]));
  outr[tid + 256] = f2b((v1 - mean) * inv * b2f(g[tid + 256]) + b2f(b[tid + 256]));
  outr[tid + 512] = f2b((v2 - mean) * inv * b2f(g[tid + 512]) + b2f(b[tid + 512]));
}

// ---------------- LayerNorm (f32 input) ----------------
__global__ __launch_bounds__(256) void ln_f32_kernel(
    const float* __restrict__ x, const u16* __restrict__ g,
    const u16* __restrict__ b, u16* __restrict__ out) {
  int row = blockIdx.x;
  int tid = threadIdx.x;
  const float* xr = x + (size_t)row * DMODEL;
  float v0 = xr[tid], v1 = xr[tid + 256], v2 = xr[tid + 512];
  float s = v0 + v1 + v2;
  float q = v0 * v0 + v1 * v1 + v2 * v2;
#pragma unroll
  for (int off = 32; off; off >>= 1) {
    s += __shfl_xor(s, off, 64);
    q += __shfl_xor(q, off, 64);
  }
  __shared__ float rs[4], rq[4];
  int wv = tid >> 6;
  if ((tid & 63) == 0) { rs[wv] = s; rq[wv] = q; }
  __syncthreads();
  s = rs[0] + rs[1] + rs[2] + rs[3];
  q = rq[0] + rq[1] + rq[2] + rq[3];
  float mean = s * (1.0f / 768.0f);
  float var = q * (1.0f / 768.0f) - mean * mean;
  float inv = rsqrtf(var + 1e-5f);
  u16* outr = out + (size_t)row * DMODEL;
  outr[tid]       = f2b((v0 - mean) * inv * b2f(g[tid])       + b2f(b[tid]));
  outr[tid + 256] = f2b((v1 - mean) * inv * b2f(g[tid + 256]) + b2f(b[tid + 256]));
  outr[tid + 512] = f2b((v2 - mean) * inv * b2f(g[tid + 512]) + b2f(b[tid + 512]));
}

// ---------------- MFMA GEMM: C = A[M,K] * W[N,K]^T + bias, bf16 out ----------
// wave = 64x64 tile (4x4 MFMA subtiles), block = 2x2 waves = 128x128.
// A-frag: lane holds A[m=lane&15][k=quad*8+j]; B-frag: B[k=quad*8+j][n=lane&15]
// C/D:    lane holds C[row=quad*4+r][col=lane&15]
__global__ __launch_bounds__(256) void gemm_bt(
    const u16* __restrict__ Ap, const u16* __restrict__ Wp,
    const u16* __restrict__ bias, u16* __restrict__ Cp, int Nn, int K) {
  const __bf16* A = (const __bf16*)Ap;
  const __bf16* W = (const __bf16*)Wp;
  int lane = threadIdx.x & 63;
  int wv = threadIdx.x >> 6;
  int q16 = lane & 15, quad = lane >> 4;
  int mBase = blockIdx.y * 128 + (wv >> 1) * 64;
  int nBase = blockIdx.x * 128 + (wv & 1) * 64;
  f32x4 acc[4][4] = {};
  for (int k0 = 0; k0 < K; k0 += 32) {
    bf16x8 af[4], bfr[4];
#pragma unroll
    for (int si = 0; si < 4; ++si)
      af[si] = *(const bf16x8*)(A + (size_t)(mBase + si * 16 + q16) * K + k0 + quad * 8);
#pragma unroll
    for (int sj = 0; sj < 4; ++sj)
      bfr[sj] = *(const bf16x8*)(W + (size_t)(nBase + sj * 16 + q16) * K + k0 + quad * 8);
#pragma unroll
    for (int si = 0; si < 4; ++si)
#pragma unroll
      for (int sj = 0; sj < 4; ++sj)
        acc[si][sj] = __builtin_amdgcn_mfma_f32_16x16x32_bf16(af[si], bfr[sj], acc[si][sj], 0, 0, 0);
  }
#pragma unroll
  for (int si = 0; si < 4; ++si)
#pragma unroll
    for (int sj = 0; sj < 4; ++sj) {
      int col = nBase + sj * 16 + q16;
      float bcol = b2f(bias[col]);
#pragma unroll
      for (int r = 0; r < 4; ++r) {
        int rowi = mBase + si * 16 + quad * 4 + r;
        Cp[(size_t)rowi * Nn + col] = f2b(acc[si][sj][r] + bcol);
      }
    }
}

// ---------------- final MFMA GEMM: out(f32) = x1 + act @ wout^T + bias -------
// N=768 -> grid (6,32); OUTPUT IS FLOAT32 (the R10 fix).
__global__ __launch_bounds__(256) void gemm_out_f32(
    const u16* __restrict__ Ap, const u16* __restrict__ Wp,
    const u16* __restrict__ bias, const float* __restrict__ res,
    float* __restrict__ Cp, int Nn, int K) {
  const __bf16* A = (const __bf16*)Ap;
  const __bf16* W = (const __bf16*)Wp;
  int lane = threadIdx.x & 63;
  int wv = threadIdx.x >> 6;
  int q16 = lane & 15, quad = lane >> 4;
  int mBase = blockIdx.y * 128 + (wv >> 1) * 64;
  int nBase = blockIdx.x * 128 + (wv & 1) * 64;
  f32x4 acc[4][4] = {};
  for (int k0 = 0; k0 < K; k0 += 32) {
    bf16x8 af[4], bfr[4];
#pragma unroll
    for (int si = 0; si < 4; ++si)
      af[si] = *(const bf16x8*)(A + (size_t)(mBase + si * 16 + q16) * K + k0 + quad * 8);
#pragma unroll
    for (int sj = 0; sj < 4; ++sj)
      bfr[sj] = *(const bf16x8*)(W + (size_t)(nBase + sj * 16 + q16) * K + k0 + quad * 8);
#pragma unroll
    for (int si = 0; si < 4; ++si)
#pragma unroll
      for (int sj = 0; sj < 4; ++sj)
        acc[si][sj] = __builtin_amdgcn_mfma_f32_16x16x32_bf16(af[si], bfr[sj], acc[si][sj], 0, 0, 0);
  }
#pragma unroll
  for (int si = 0; si < 4; ++si)
#pragma unroll
    for (int sj = 0; sj < 4; ++sj) {
      int col = nBase + sj * 16 + q16;
      float bcol = b2f(bias[col]);
#pragma unroll
      for (int r = 0; r < 4; ++r) {
        int rowi = mBase + si * 16 + quad * 4 + r;
        Cp[(size_t)rowi * Nn + col] = acc[si][sj][r] + bcol + res[(size_t)rowi * Nn + col];
      }
    }
}

// ---------------- fused FFN-in: act = silu(h2 @ Wu^T + bu) * (h2 @ Wg^T + bg)
__global__ __launch_bounds__(256) void ffn_in_kernel(
    const u16* __restrict__ hp, const u16* __restrict__ Wp,
    const u16* __restrict__ bias, u16* __restrict__ actp) {
  const __bf16* A = (const __bf16*)hp;
  const __bf16* W = (const __bf16*)Wp;
  int lane = threadIdx.x & 63;
  int wv = threadIdx.x >> 6;
  int q16 = lane & 15, quad = lane >> 4;
  int mBase = blockIdx.y * 128 + (wv >> 1) * 64;
  int cBase = blockIdx.x * 64 + (wv & 1) * 32;
  f32x4 au[4][2] = {}, ag[4][2] = {};
  for (int k0 = 0; k0 < DMODEL; k0 += 32) {
    bf16x8 af[4], wu[2], wg[2];
#pragma unroll
    for (int si = 0; si < 4; ++si)
      af[si] = *(const bf16x8*)(A + (size_t)(mBase + si * 16 + q16) * DMODEL + k0 + quad * 8);
#pragma unroll
    for (int sj = 0; sj < 2; ++sj) {
      wu[sj] = *(const bf16x8*)(W + (size_t)(cBase + sj * 16 + q16) * DMODEL + k0 + quad * 8);
      wg[sj] = *(const bf16x8*)(W + (size_t)(HIDDIM + cBase + sj * 16 + q16) * DMODEL + k0 + quad * 8);
    }
#pragma unroll
    for (int si = 0; si < 4; ++si)
#pragma unroll
      for (int sj = 0; sj < 2; ++sj) {
        au[si][sj] = __builtin_amdgcn_mfma_f32_16x16x32_bf16(af[si], wu[sj], au[si][sj], 0, 0, 0);
        ag[si][sj] = __builtin_amdgcn_mfma_f32_16x16x32_bf16(af[si], wg[sj], ag[si][sj], 0, 0, 0);
      }
  }
#pragma unroll
  for (int si = 0; si < 4; ++si)
#pragma unroll
    for (int sj = 0; sj < 2; ++sj) {
      int col = cBase + sj * 16 + q16;
      float bu = b2f(bias[col]);
      float bg = b2f(bias[HIDDIM + col]);
#pragma unroll
      for (int r = 0; r < 4; ++r) {
        int rowi = mBase + si * 16 + quad * 4 + r;
        float u = au[si][sj][r] + bu;
        float g = ag[si][sj][r] + bg;
        float s = u / (1.0f + __expf(-u));
        actp[(size_t)rowi * HIDDIM + col] = f2b(s * g);
      }
    }
}

// ---------------- coord bias p[b,h,n] ----------------------------------------
__global__ __launch_bounds__(256) void p_kernel(
    const u16* __restrict__ coords, const u16* __restrict__ relw,
    float* __restrict__ p) {
  int idx = blockIdx.x * 256 + threadIdx.x;  // B*N = 4096
  float c0 = b2f(coords[idx * 3 + 0]);
  float c1 = b2f(coords[idx * 3 + 1]);
  float c2 = b2f(coords[idx * 3 + 2]);
  int b = idx >> 10, n = idx & 1023;
#pragma unroll
  for (int h = 0; h < NHEAD; ++h) {
    float w0 = b2f(relw[h * 3 + 0]), w1 = b2f(relw[h * 3 + 1]), w2 = b2f(relw[h * 3 + 2]);
    p[(size_t)(b * NHEAD + h) * NTOK + n] = c0 * w0 + c1 * w1 + c2 * w2;
  }
}

// ---------------- flash attention + residual: x1 = x + attn_out (fp32) -------
// 3072 waves: 4 batches x 12 heads x 64 query-tiles of 16
__global__ __launch_bounds__(256) void attn_kernel(
    const u16* __restrict__ qkvp, const float* __restrict__ p,
    const u16* __restrict__ xp, float* __restrict__ x1) {
  const __bf16* qb = (const __bf16*)qkvp;
  __shared__ __align__(16) __bf16 Plds[4][16][32];
  int lane = threadIdx.x & 63;
  int wv = threadIdx.x >> 6;
  int wave = blockIdx.x * 4 + wv;          // 0..3071
  int b = wave / 768;
  int rem = wave % 768;
  int h = rem >> 6;
  int i0 = (rem & 63) * 16;
  int q16 = lane & 15, quad = lane >> 4;

  const float LOG2E = 1.4426950408889634f;
  const float scl2 = 0.125f * LOG2E;

  const __bf16* qrow = qb + ((size_t)(b * NTOK) + i0 + q16) * LD3 + h * 64;
  bf16x8 aq0 = *(const bf16x8*)(qrow + quad * 8);
  bf16x8 aq1 = *(const bf16x8*)(qrow + 32 + quad * 8);

  const float* prow = p + (size_t)(b * NHEAD + h) * NTOK;
  float pil2[4];
#pragma unroll
  for (int r = 0; r < 4; ++r) pil2[r] = prow[i0 + quad * 4 + r] * LOG2E;

  float m2[4] = {-1e30f, -1e30f, -1e30f, -1e30f};
  float lsum[4] = {0.f, 0.f, 0.f, 0.f};
  f32x4 accO[4] = {};

  for (int j0 = 0; j0 < NTOK; j0 += 32) {
    const __bf16* krow0 = qb + ((size_t)(b * NTOK) + j0 + q16) * LD3 + DMODEL + h * 64;
    const __bf16* krow1 = krow0 + (size_t)16 * LD3;
    bf16x8 kb00 = *(const bf16x8*)(krow0 + quad * 8);
    bf16x8 kb01 = *(const bf16x8*)(krow0 + 32 + quad * 8);
    bf16x8 kb10 = *(const bf16x8*)(krow1 + quad * 8);
    bf16x8 kb11 = *(const bf16x8*)(krow1 + 32 + quad * 8);
    f32x4 s0 = {}, s1 = {};
    s0 = __builtin_amdgcn_mfma_f32_16x16x32_bf16(aq0, kb00, s0, 0, 0, 0);
    s0 = __builtin_amdgcn_mfma_f32_16x16x32_bf16(aq1, kb01, s0, 0, 0, 0);
    s1 = __builtin_amdgcn_mfma_f32_16x16x32_bf16(aq0, kb10, s1, 0, 0, 0);
    s1 = __builtin_amdgcn_mfma_f32_16x16x32_bf16(aq1, kb11, s1, 0, 0, 0);

    float pj0 = prow[j0 + q16] * LOG2E;
    float pj1 = prow[j0 + 16 + q16] * LOG2E;
    float sv0[4], sv1[4], ps0[4], ps1[4], alpha[4];
#pragma unroll
    for (int r = 0; r < 4; ++r) {
      sv0[r] = s0[r] * scl2 + pil2[r] - pj0;
      sv1[r] = s1[r] * scl2 + pil2[r] - pj1;
    }
#pragma unroll
    for (int r = 0; r < 4; ++r) {
      float t = fmaxf(sv0[r], sv1[r]);
      t = fmaxf(t, __shfl_xor(t, 1, 16));
      t = fmaxf(t, __shfl_xor(t, 2, 16));
      t = fmaxf(t, __shfl_xor(t, 4, 16));
      t = fmaxf(t, __shfl_xor(t, 8, 16));
      float mn = fmaxf(m2[r], t);
      alpha[r] = exp2f(m2[r] - mn);
      m2[r] = mn;
      ps0[r] = exp2f(sv0[r] - mn);
      ps1[r] = exp2f(sv1[r] - mn);
      float srow = ps0[r] + ps1[r];
      srow += __shfl_xor(srow, 1, 16);
      srow += __shfl_xor(srow, 2, 16);
      srow += __shfl_xor(srow, 4, 16);
      srow += __shfl_xor(srow, 8, 16);
      lsum[r] = lsum[r] * alpha[r] + srow;
    }
    __syncthreads();
#pragma unroll
    for (int r = 0; r < 4; ++r) {
      Plds[wv][quad * 4 + r][q16] = (__bf16)ps0[r];
      Plds[wv][quad * 4 + r][16 + q16] = (__bf16)ps1[r];
    }
    __syncthreads();
    bf16x8 ap = *(const bf16x8*)(&Plds[wv][q16][quad * 8]);

    const __bf16* vrow = qb + ((size_t)(b * NTOK) + j0 + quad * 8) * LD3 + 2 * DMODEL + h * 64;
#pragma unroll
    for (int ds = 0; ds < 4; ++ds) {
      bf16x8 bv;
#pragma unroll
      for (int jj = 0; jj < 8; ++jj) bv[jj] = vrow[(size_t)jj * LD3 + ds * 16 + q16];
      f32x4 c = accO[ds];
#pragma unroll
      for (int r = 0; r < 4; ++r) c[r] *= alpha[r];
      accO[ds] = __builtin_amdgcn_mfma_f32_16x16x32_bf16(ap, bv, c, 0, 0, 0);
    }
  }
#pragma unroll
  for (int ds = 0; ds < 4; ++ds)
#pragma unroll
    for (int r = 0; r < 4; ++r) {
      size_t idx = ((size_t)(b * NTOK) + i0 + quad * 4 + r) * DMODEL + h * 64 + ds * 16 + q16;
      x1[idx] = b2f(xp[idx]) + accO[ds][r] / lsum[r];
    }
}

extern "C" void kernel_launch(void* const* d_in, const int* in_sizes, int n_in,
                              void* d_out, int out_size, void* d_ws, size_t ws_size,
                              hipStream_t stream) {
  // ---- host-side boundary tripwires (verified passing in R6) ----
  static const int esz[13] = {3145728, 12288, 768, 768, 1769472, 2304, 36,
                              768, 768, 3145728, 4096, 1572864, 768};
  float sig = -1.f;
  if (n_in != 13) {
    sig = 6000.f + 100.f * (float)n_in;
  } else {
    for (int i = 0; i < 13; ++i)
      if (in_sizes[i] != esz[i]) { sig = 1000.f + 100.f * (float)i; break; }
  }
  if (sig < 0.f && ws_size < 57258496ULL) sig = 3000.f;
  if (sig < 0.f && out_size != 3145728) sig = 3100.f;
  if (sig >= 0.f) {
    signal_kernel<<<(out_size + 255) / 256, 256, 0, stream>>>((float*)d_out, out_size, sig);
    return;
  }

  char* ws = (char*)d_ws;
  int*  flag    = (int*)ws;                       // 256 B
  u16*  cx      = (u16*)(ws + 256);               // 6291456
  u16*  cqkvw   = (u16*)(ws + 6291712);           // 3538944
  u16*  cwinw   = (u16*)(ws + 9830656);           // 6291456
  u16*  cwoutw  = (u16*)(ws + 16122112);          // 3145728
  u16*  ccoords = (u16*)(ws + 19267840);          // 24576
  u16*  cln1g   = (u16*)(ws + 19292416);          // 1536
  u16*  cln1b   = (u16*)(ws + 19293952);          // 1536
  u16*  cqkvb   = (u16*)(ws + 19295488);          // 4608
  u16*  crelw   = (u16*)(ws + 19300096);          // 72 (padded)
  u16*  cln2g   = (u16*)(ws + 19300352);          // 1536
  u16*  cln2b   = (u16*)(ws + 19301888);          // 1536
  u16*  cwinb   = (u16*)(ws + 19303424);          // 8192
  u16*  cwoutb  = (u16*)(ws + 19311616);          // 1536
  u16*  h       = (u16*)(ws + 19313152);          // 6291456
  u16*  qkv     = (u16*)(ws + 25604608);          // 18874368 (reused as act)
  float* pbuf   = (float*)(ws + 44478976);        // 196608
  float* x1     = (float*)(ws + 44675584);        // 12582912 -> end 57258496
  u16*  act     = qkv;

  // 0a. dtype flag (f32 confirmed; adaptive kept as insurance)
  detect_kernel<<<1, 256, 0, stream>>>((const u16*)d_in[0], flag);

  // 0b. canonicalize all 13 inputs to bf16 (linear C-order)
  CanonJobs jobs;
  u16* dsts[13] = {cx, ccoords, cln1g, cln1b, cqkvw, cqkvb, crelw,
                   cln2g, cln2b, cwinw, cwinb, cwoutw, cwoutb};
  for (int i = 0; i < 13; ++i) {
    jobs.s[i] = d_in[i];
    jobs.d[i] = dsts[i];
    jobs.n[i] = in_sizes[i];
  }
  canon_kernel<<<dim3(3072, 13), 256, 0, stream>>>(jobs, flag);

  // 1. h = LN1(x)
  ln_bf16_kernel<<<4096, 256, 0, stream>>>(cx, cln1g, cln1b, h);
  // 2. qkv = h @ qkv_w^T + qkv_b   (M=4096, N=2304, K=768)
  gemm_bt<<<dim3(18, 32), 256, 0, stream>>>(h, cqkvw, cqkvb, qkv, 2304, 768);
  // 3. p[b,h,n]
  p_kernel<<<16, 256, 0, stream>>>(ccoords, crelw, pbuf);
  // 4. x1 = x + attention(qkv, p)   (3072 waves / 768 blocks)
  attn_kernel<<<768, 256, 0, stream>>>(qkv, pbuf, cx, x1);
  // 5. h2 = LN2(x1)  (reuse h)
  ln_f32_kernel<<<4096, 256, 0, stream>>>(x1, cln2g, cln2b, h);
  // 6+7. act = silu(h2 @ Wu^T + bu) * (h2 @ Wg^T + bg)   (fused)
  ffn_in_kernel<<<dim3(32, 32), 256, 0, stream>>>(h, cwinw, cwinb, act);
  // 8. out(F32) = x1 + act @ wout_w^T + wout_b   (M=4096, N=768, K=2048)
  gemm_out_f32<<<dim3(6, 32), 256, 0, stream>>>(act, cwoutw, cwoutb, x1, (float*)d_out, 768, 2048);
}